// Round 5
// baseline (833.542 us; speedup 1.0000x reference)
//
#include <hip/hip_runtime.h>
#include <hip/hip_bf16.h>
#include <cstdint>

#define NNODES 100000
#define NEDGES 1000000
#define HDIM 64
#define ODIM 16
#define NB 8
#define KDIM (HDIM * NB)   // 512 = GEMM inner dim, k = i*8 + b

typedef short short8 __attribute__((ext_vector_type(8)));
typedef float f32x4  __attribute__((ext_vector_type(4)));
typedef unsigned int uint4v __attribute__((ext_vector_type(4)));
union FragU { uint4 u; uint4v v; short8 s; };

__device__ __forceinline__ float asf(uint32_t u) { float f; __builtin_memcpy(&f, &u, 4); return f; }
__device__ __forceinline__ uint32_t asu(float f) { uint32_t u; __builtin_memcpy(&u, &f, 4); return u; }
__device__ __forceinline__ uint16_t f2bf(float f) {
    uint32_t x = asu(f);
    return (uint16_t)((x + 0x7FFFu + ((x >> 16) & 1u)) >> 16);
}
__device__ __forceinline__ uint32_t pack2(float lo, float hi) {
    return (uint32_t)f2bf(lo) | ((uint32_t)f2bf(hi) << 16);
}
__device__ __forceinline__ void fmaC(const float4& cA, const float4& cB, float xs,
                                     float* __restrict__ acc) {
    acc[0] = fmaf(cA.x, xs, acc[0]); acc[1] = fmaf(cA.y, xs, acc[1]);
    acc[2] = fmaf(cA.z, xs, acc[2]); acc[3] = fmaf(cA.w, xs, acc[3]);
    acc[4] = fmaf(cB.x, xs, acc[4]); acc[5] = fmaf(cB.y, xs, acc[5]);
    acc[6] = fmaf(cB.z, xs, acc[6]); acc[7] = fmaf(cB.w, xs, acc[7]);
}

// ---------------------------------------------------------------------------
// cast: f32 feats -> bf16 x  (4 elems/thread)
// ---------------------------------------------------------------------------
__global__ void cast_kernel(const float* __restrict__ in, uint16_t* __restrict__ out, int n4) {
    const int stride = (int)(gridDim.x * blockDim.x);
    for (int idx = (int)(blockIdx.x * blockDim.x + threadIdx.x); idx < n4; idx += stride) {
        float4 v = reinterpret_cast<const float4*>(in)[idx];
        uint2 p;
        p.x = pack2(v.x, v.y);
        p.y = pack2(v.z, v.w);
        reinterpret_cast<uint2*>(out)[idx] = p;
    }
}

// ---------------------------------------------------------------------------
// CSR build: histogram by dst -> exclusive scan -> scatter packed edge recs
// ---------------------------------------------------------------------------
__global__ void zero_kernel(int* __restrict__ p, int n) {
    for (int i = (int)(blockIdx.x * blockDim.x + threadIdx.x); i < n;
         i += (int)(gridDim.x * blockDim.x)) p[i] = 0;
}

__global__ void hist_kernel(const int* __restrict__ dst, int* __restrict__ cnt, int nE) {
    for (int e = (int)(blockIdx.x * blockDim.x + threadIdx.x); e < nE;
         e += (int)(gridDim.x * blockDim.x)) atomicAdd(&cnt[dst[e]], 1);
}

#define SCAN_B 512
__launch_bounds__(SCAN_B)
__global__ void scan_partial_kernel(const int* __restrict__ cnt, int* __restrict__ bsum, int n) {
    __shared__ int sh[SCAN_B];
    int id = (int)(blockIdx.x * SCAN_B + threadIdx.x);
    sh[threadIdx.x] = (id < n) ? cnt[id] : 0;
    __syncthreads();
    for (int off = SCAN_B / 2; off > 0; off >>= 1) {
        if ((int)threadIdx.x < off) sh[threadIdx.x] += sh[threadIdx.x + off];
        __syncthreads();
    }
    if (threadIdx.x == 0) bsum[blockIdx.x] = sh[0];
}

// parallel scan over block sums (nblk <= 256), one block of 256 threads
__launch_bounds__(256)
__global__ void scan_base_kernel(const int* __restrict__ bsum, int* __restrict__ bbase,
                                 int* __restrict__ offs, int nblk, int nNodes) {
    __shared__ int sh[256];
    const int t = (int)threadIdx.x;
    int v = (t < nblk) ? bsum[t] : 0;
    sh[t] = v;
    __syncthreads();
    for (int off = 1; off < 256; off <<= 1) {
        int tmp = (t >= off) ? sh[t - off] : 0;
        __syncthreads();
        sh[t] += tmp;
        __syncthreads();
    }
    if (t < nblk) bbase[t] = sh[t] - v;       // exclusive base per block
    if (t == 255) offs[nNodes] = sh[255];     // grand total
}

__launch_bounds__(SCAN_B)
__global__ void scan_final_kernel(int* __restrict__ cnt, const int* __restrict__ bbase,
                                  int* __restrict__ offs, int n) {
    __shared__ int sh[SCAN_B];
    int id = (int)(blockIdx.x * SCAN_B + threadIdx.x);
    int v = (id < n) ? cnt[id] : 0;
    sh[threadIdx.x] = v;
    __syncthreads();
    for (int off = 1; off < SCAN_B; off <<= 1) {
        int tmp = ((int)threadIdx.x >= off) ? sh[threadIdx.x - off] : 0;
        __syncthreads();
        sh[threadIdx.x] += tmp;
        __syncthreads();
    }
    if (id < n) {
        int excl = sh[threadIdx.x] - v + bbase[blockIdx.x];
        offs[id] = excl;
        cnt[id]  = excl;   // becomes the scatter cursor
    }
}

__global__ void scatter_kernel(const int* __restrict__ src, const int* __restrict__ dst,
                               const int* __restrict__ et, const float* __restrict__ norm,
                               int* __restrict__ cursor, uint4* __restrict__ rec, int nE) {
    for (int e = (int)(blockIdx.x * blockDim.x + threadIdx.x); e < nE;
         e += (int)(gridDim.x * blockDim.x)) {
        int p = atomicAdd(&cursor[dst[e]], 1);
        rec[p] = make_uint4((uint32_t)src[e], (uint32_t)et[e], asu(norm[e]), 0u);
    }
}

// ---------------------------------------------------------------------------
// Input-space aggregation: G[d][i][b] = sum_{e in in(d)} norm_e*coeff[r_e,b]*x[src_e,i]
// One wave per dst node; lane = i. Unroll-4: four independent rec->x chains in
// flight. NT on rec loads + G stores to keep the 12.8MB x array L2-resident.
// ---------------------------------------------------------------------------
__launch_bounds__(256)
__global__ void csr_agg_kernel(const uint16_t* __restrict__ x,
                               const float* __restrict__ coeff,
                               const int* __restrict__ offs,
                               const uint4v* __restrict__ rec,
                               uint16_t* __restrict__ G, int nNodes) {
    const int lane = threadIdx.x & 63;
    const int wid  = (int)((blockIdx.x * blockDim.x + threadIdx.x) >> 6);
    const int nw   = (int)((gridDim.x * blockDim.x) >> 6);
    for (int d = wid; d < nNodes; d += nw) {
        const int j0 = offs[d], j1 = offs[d + 1];
        float acc[NB] = {0.f, 0.f, 0.f, 0.f, 0.f, 0.f, 0.f, 0.f};
        int j = j0;
        for (; j + 4 <= j1; j += 4) {
            const uint4v r0 = __builtin_nontemporal_load(rec + j);
            const uint4v r1 = __builtin_nontemporal_load(rec + j + 1);
            const uint4v r2 = __builtin_nontemporal_load(rec + j + 2);
            const uint4v r3 = __builtin_nontemporal_load(rec + j + 3);
            const float xv0 = asf((uint32_t)x[(size_t)r0.x * HDIM + lane] << 16);
            const float xv1 = asf((uint32_t)x[(size_t)r1.x * HDIM + lane] << 16);
            const float xv2 = asf((uint32_t)x[(size_t)r2.x * HDIM + lane] << 16);
            const float xv3 = asf((uint32_t)x[(size_t)r3.x * HDIM + lane] << 16);
            const float4 cA0 = *reinterpret_cast<const float4*>(coeff + r0.y * NB);
            const float4 cB0 = *reinterpret_cast<const float4*>(coeff + r0.y * NB + 4);
            const float4 cA1 = *reinterpret_cast<const float4*>(coeff + r1.y * NB);
            const float4 cB1 = *reinterpret_cast<const float4*>(coeff + r1.y * NB + 4);
            const float4 cA2 = *reinterpret_cast<const float4*>(coeff + r2.y * NB);
            const float4 cB2 = *reinterpret_cast<const float4*>(coeff + r2.y * NB + 4);
            const float4 cA3 = *reinterpret_cast<const float4*>(coeff + r3.y * NB);
            const float4 cB3 = *reinterpret_cast<const float4*>(coeff + r3.y * NB + 4);
            fmaC(cA0, cB0, asf(r0.z) * xv0, acc);
            fmaC(cA1, cB1, asf(r1.z) * xv1, acc);
            fmaC(cA2, cB2, asf(r2.z) * xv2, acc);
            fmaC(cA3, cB3, asf(r3.z) * xv3, acc);
        }
        for (; j < j1; j++) {
            const uint4v r0 = __builtin_nontemporal_load(rec + j);
            const float xv0 = asf((uint32_t)x[(size_t)r0.x * HDIM + lane] << 16);
            const float4 cA0 = *reinterpret_cast<const float4*>(coeff + r0.y * NB);
            const float4 cB0 = *reinterpret_cast<const float4*>(coeff + r0.y * NB + 4);
            fmaC(cA0, cB0, asf(r0.z) * xv0, acc);
        }
        uint4v pv;
        pv.x = pack2(acc[0], acc[1]);
        pv.y = pack2(acc[2], acc[3]);
        pv.z = pack2(acc[4], acc[5]);
        pv.w = pack2(acc[6], acc[7]);
        __builtin_nontemporal_store(pv,
            reinterpret_cast<uint4v*>(G + (size_t)d * KDIM + lane * NB));
    }
}

// ---------------------------------------------------------------------------
// MFMA GEMM: [N,512] bf16 (G) x [512,64] bf16 (bases) -> xout bf16 (+bias,relu)
// mfma_f32_16x16x32_bf16: A[m=lane&15][k=(lane>>4)*8+j], B[k][n=lane&15],
// C col=lane&15, row=(lane>>4)*4+reg.
// Block = 512 thr = 8 waves: wave w -> (rowgrp=w>>2)*16 rows, o-tile=w&3.
// Each wave holds its 16 B-fragments in REGISTERS (loaded from LDS once) --
// the K-loop is pure global-A-load + MFMA, no LDS.
// ---------------------------------------------------------------------------
__launch_bounds__(512)
__global__ void proj_hidden_kernel(const uint16_t* __restrict__ G,
                                   const float* __restrict__ bases,
                                   const float* __restrict__ bias,
                                   uint16_t* __restrict__ xout, int nNodes) {
    constexpr int OT = HDIM / 16;       // 4 o-tiles
    __shared__ __align__(16) uint16_t Wf[16 * OT * 64 * 8];   // 64 KB

    const int t    = (int)threadIdx.x;
    const int lane = t & 63;
    const int w    = t >> 6;
    const int ot   = w & 3;
    const int rg   = w >> 2;            // 0..1
    const int q    = lane >> 4;
    const int c    = lane & 15;

    // Stage bases into B-fragment order: Wf[((kb*OT+ot)*64+lane)*8+j] =
    //   bf16(bases[b][i][o]) with k=kb*32+(lane>>4)*8+j, o=ot*16+(lane&15).
    for (int idx = t; idx < 16 * OT * 64 * 8; idx += 512) {
        int j    = idx & 7;
        int ln   = (idx >> 3) & 63;
        int rest = idx >> 9;            // kb*OT + ot
        int o_t  = rest & (OT - 1);
        int kb   = rest >> 2;
        int k    = kb * 32 + (ln >> 4) * 8 + j;
        int o    = o_t * 16 + (ln & 15);
        int i    = k >> 3, b = k & 7;
        Wf[idx] = f2bf(bases[(size_t)(b * HDIM + i) * HDIM + o]);
    }
    __syncthreads();

    // This wave's 16 B-fragments -> registers
    FragU bfr[16];
#pragma unroll
    for (int kb = 0; kb < 16; kb++)
        bfr[kb].u = *reinterpret_cast<const uint4*>(Wf + ((kb * OT + ot) * 64 + lane) * 8);

    const float bv = bias[ot * 16 + c];

    const int nTiles = (nNodes + 31) / 32;
    for (int tile = blockIdx.x; tile < nTiles; tile += gridDim.x) {
        const int n0 = tile * 32 + rg * 16;
        int arow = n0 + c;
        if (arow > nNodes - 1) arow = nNodes - 1;
        const uint16_t* gp = G + (size_t)arow * KDIM + q * 8;

        f32x4 acc = {0.f, 0.f, 0.f, 0.f};
#pragma unroll
        for (int kb = 0; kb < 16; kb++) {
            FragU a;
            a.v = __builtin_nontemporal_load(reinterpret_cast<const uint4v*>(gp + kb * 32));
            acc = __builtin_amdgcn_mfma_f32_16x16x32_bf16(a.s, bfr[kb].s, acc, 0, 0, 0);
        }

#pragma unroll
        for (int r = 0; r < 4; r++) {
            const int node = n0 + q * 4 + r;
            if (node < nNodes) {
                float v = fmaxf(acc[r] + bv, 0.f);
                xout[(size_t)node * HDIM + ot * 16 + c] = f2bf(v);
            }
        }
    }
}

// Same structure, DOUT=16 (single o-tile), f32 output, no relu.
// Block = 256 thr = 4 waves: wave w -> rows w*16 of a 64-node tile.
__launch_bounds__(256)
__global__ void proj_out_kernel(const uint16_t* __restrict__ G,
                                const float* __restrict__ bases,
                                const float* __restrict__ bias,
                                float* __restrict__ out, int nNodes) {
    __shared__ __align__(16) uint16_t Wf[16 * 64 * 8];   // 16 KB

    const int t    = (int)threadIdx.x;
    const int lane = t & 63;
    const int w    = t >> 6;            // 0..3 rowgroup
    const int q    = lane >> 4;
    const int c    = lane & 15;

    for (int idx = t; idx < 16 * 64 * 8; idx += 256) {
        int j  = idx & 7;
        int ln = (idx >> 3) & 63;
        int kb = idx >> 9;
        int k  = kb * 32 + (ln >> 4) * 8 + j;
        int o  = ln & 15;
        int i  = k >> 3, b = k & 7;
        Wf[idx] = f2bf(bases[(size_t)(b * HDIM + i) * ODIM + o]);
    }
    __syncthreads();

    FragU bfr[16];
#pragma unroll
    for (int kb = 0; kb < 16; kb++)
        bfr[kb].u = *reinterpret_cast<const uint4*>(Wf + (kb * 64 + lane) * 8);

    const float bv = bias[c];

    const int nTiles = (nNodes + 63) / 64;
    for (int tile = blockIdx.x; tile < nTiles; tile += gridDim.x) {
        const int n0 = tile * 64 + w * 16;
        int arow = n0 + c;
        if (arow > nNodes - 1) arow = nNodes - 1;
        const uint16_t* gp = G + (size_t)arow * KDIM + q * 8;

        f32x4 acc = {0.f, 0.f, 0.f, 0.f};
#pragma unroll
        for (int kb = 0; kb < 16; kb++) {
            FragU a;
            a.v = __builtin_nontemporal_load(reinterpret_cast<const uint4v*>(gp + kb * 32));
            acc = __builtin_amdgcn_mfma_f32_16x16x32_bf16(a.s, bfr[kb].s, acc, 0, 0, 0);
        }

#pragma unroll
        for (int r = 0; r < 4; r++) {
            const int node = n0 + q * 4 + r;
            if (node < nNodes) out[(size_t)node * ODIM + c] = acc[r] + bv;
        }
    }
}

extern "C" void kernel_launch(void* const* d_in, const int* in_sizes, int n_in,
                              void* d_out, int out_size, void* d_ws, size_t ws_size,
                              hipStream_t stream) {
    const float* feats  = (const float*)d_in[0];
    const float* coeff0 = (const float*)d_in[1];
    const float* bases0 = (const float*)d_in[2];
    const float* bias0  = (const float*)d_in[3];
    const float* coeff1 = (const float*)d_in[4];
    const float* bases1 = (const float*)d_in[5];
    const float* bias1  = (const float*)d_in[6];
    const float* coeff2 = (const float*)d_in[7];
    const float* bases2 = (const float*)d_in[8];
    const float* bias2  = (const float*)d_in[9];
    const int*   src    = (const int*)d_in[10];
    const int*   dst    = (const int*)d_in[11];
    const int*   etype  = (const int*)d_in[12];
    const float* norm   = (const float*)d_in[13];
    float* out = (float*)d_out;

    char* base = (char*)d_ws;
    // layout: G 102.4MB | x 12.8MB | offs | cursor | bsum | bbase | rec 16MB
    uint16_t* G = (uint16_t*)base;
    uint16_t* x = (uint16_t*)(base + (size_t)NNODES * KDIM * 2);       // +102,400,000
    const size_t OFF_OFFS  = 115200000;
    const size_t OFF_CURS  = OFF_OFFS + 400016;
    const size_t OFF_BSUM  = OFF_CURS + 400016;
    const size_t OFF_BBASE = OFF_BSUM + 1024;
    const size_t OFF_REC   = OFF_BBASE + 1024;
    int*    offs  = (int*)(base + OFF_OFFS);
    int*    curs  = (int*)(base + OFF_CURS);
    int*    bsum  = (int*)(base + OFF_BSUM);
    int*    bbase = (int*)(base + OFF_BBASE);
    uint4*  rec   = (uint4*)(base + OFF_REC);
    uint4v* recv  = (uint4v*)(base + OFF_REC);

    const int nblk = (NNODES + SCAN_B - 1) / SCAN_B;   // 196 <= 256

    // ---- CSR build (graph identical across layers; built once per call)
    hipLaunchKernelGGL(zero_kernel, dim3(256), dim3(256), 0, stream, curs, NNODES);
    hipLaunchKernelGGL(hist_kernel, dim3(2048), dim3(256), 0, stream, dst, curs, NEDGES);
    hipLaunchKernelGGL(scan_partial_kernel, dim3(nblk), dim3(SCAN_B), 0, stream, curs, bsum, NNODES);
    hipLaunchKernelGGL(scan_base_kernel, dim3(1), dim3(256), 0, stream, bsum, bbase, offs, nblk, NNODES);
    hipLaunchKernelGGL(scan_final_kernel, dim3(nblk), dim3(SCAN_B), 0, stream, curs, bbase, offs, NNODES);
    hipLaunchKernelGGL(scatter_kernel, dim3(2048), dim3(256), 0, stream,
                       src, dst, etype, norm, curs, rec, NEDGES);

    // ---- x0 = bf16(feats)
    hipLaunchKernelGGL(cast_kernel, dim3(2048), dim3(256), 0, stream,
                       feats, x, NNODES * HDIM / 4);

    // ---- Layer 0
    hipLaunchKernelGGL(csr_agg_kernel, dim3(2048), dim3(256), 0, stream,
                       x, coeff0, offs, recv, G, NNODES);
    hipLaunchKernelGGL(proj_hidden_kernel, dim3(1024), dim3(512), 0, stream,
                       G, bases0, bias0, x, NNODES);
    // ---- Layer 1
    hipLaunchKernelGGL(csr_agg_kernel, dim3(2048), dim3(256), 0, stream,
                       x, coeff1, offs, recv, G, NNODES);
    hipLaunchKernelGGL(proj_hidden_kernel, dim3(1024), dim3(512), 0, stream,
                       G, bases1, bias1, x, NNODES);
    // ---- Layer 2
    hipLaunchKernelGGL(csr_agg_kernel, dim3(2048), dim3(256), 0, stream,
                       x, coeff2, offs, recv, G, NNODES);
    hipLaunchKernelGGL(proj_out_kernel, dim3(1024), dim3(256), 0, stream,
                       G, bases2, bias2, out, NNODES);
}

// Round 6
// 692.542 us; speedup vs baseline: 1.2036x; 1.2036x over previous
//
#include <hip/hip_runtime.h>
#include <hip/hip_bf16.h>
#include <cstdint>

#define NNODES 100000
#define NEDGES 1000000
#define HDIM 64
#define ODIM 16
#define NB 8
#define KDIM (HDIM * NB)   // 512 = GEMM inner dim, k = i*8 + b

typedef short short8 __attribute__((ext_vector_type(8)));
typedef float f32x4  __attribute__((ext_vector_type(4)));
union FragU { uint4 u; short8 s; };

__device__ __forceinline__ float asf(uint32_t u) { float f; __builtin_memcpy(&f, &u, 4); return f; }
__device__ __forceinline__ uint32_t asu(float f) { uint32_t u; __builtin_memcpy(&u, &f, 4); return u; }
__device__ __forceinline__ uint16_t f2bf(float f) {
    uint32_t x = asu(f);
    return (uint16_t)((x + 0x7FFFu + ((x >> 16) & 1u)) >> 16);
}
__device__ __forceinline__ uint32_t pack2(float lo, float hi) {
    return (uint32_t)f2bf(lo) | ((uint32_t)f2bf(hi) << 16);
}
__device__ __forceinline__ void fmaC(const float4& cA, const float4& cB, float xs,
                                     float* __restrict__ acc) {
    acc[0] = fmaf(cA.x, xs, acc[0]); acc[1] = fmaf(cA.y, xs, acc[1]);
    acc[2] = fmaf(cA.z, xs, acc[2]); acc[3] = fmaf(cA.w, xs, acc[3]);
    acc[4] = fmaf(cB.x, xs, acc[4]); acc[5] = fmaf(cB.y, xs, acc[5]);
    acc[6] = fmaf(cB.z, xs, acc[6]); acc[7] = fmaf(cB.w, xs, acc[7]);
}

// ---------------------------------------------------------------------------
// cast: f32 feats -> bf16 x  (4 elems/thread)
// ---------------------------------------------------------------------------
__global__ void cast_kernel(const float* __restrict__ in, uint16_t* __restrict__ out, int n4) {
    const int stride = (int)(gridDim.x * blockDim.x);
    for (int idx = (int)(blockIdx.x * blockDim.x + threadIdx.x); idx < n4; idx += stride) {
        float4 v = reinterpret_cast<const float4*>(in)[idx];
        uint2 p;
        p.x = pack2(v.x, v.y);
        p.y = pack2(v.z, v.w);
        reinterpret_cast<uint2*>(out)[idx] = p;
    }
}

// ---------------------------------------------------------------------------
// CSR build: histogram by dst -> exclusive scan -> scatter packed edge recs
// rec[e] = { src | (etype<<20), norm }  (8 B)
// ---------------------------------------------------------------------------
__global__ void zero_kernel(int* __restrict__ p, int n) {
    for (int i = (int)(blockIdx.x * blockDim.x + threadIdx.x); i < n;
         i += (int)(gridDim.x * blockDim.x)) p[i] = 0;
}

__global__ void hist_kernel(const int* __restrict__ dst, int* __restrict__ cnt, int nE) {
    for (int e = (int)(blockIdx.x * blockDim.x + threadIdx.x); e < nE;
         e += (int)(gridDim.x * blockDim.x)) atomicAdd(&cnt[dst[e]], 1);
}

#define SCAN_B 512
__launch_bounds__(SCAN_B)
__global__ void scan_partial_kernel(const int* __restrict__ cnt, int* __restrict__ bsum, int n) {
    __shared__ int sh[SCAN_B];
    int id = (int)(blockIdx.x * SCAN_B + threadIdx.x);
    sh[threadIdx.x] = (id < n) ? cnt[id] : 0;
    __syncthreads();
    for (int off = SCAN_B / 2; off > 0; off >>= 1) {
        if ((int)threadIdx.x < off) sh[threadIdx.x] += sh[threadIdx.x + off];
        __syncthreads();
    }
    if (threadIdx.x == 0) bsum[blockIdx.x] = sh[0];
}

// parallel scan over block sums (nblk <= 256), one block of 256 threads
__launch_bounds__(256)
__global__ void scan_base_kernel(const int* __restrict__ bsum, int* __restrict__ bbase,
                                 int* __restrict__ offs, int nblk, int nNodes) {
    __shared__ int sh[256];
    const int t = (int)threadIdx.x;
    int v = (t < nblk) ? bsum[t] : 0;
    sh[t] = v;
    __syncthreads();
    for (int off = 1; off < 256; off <<= 1) {
        int tmp = (t >= off) ? sh[t - off] : 0;
        __syncthreads();
        sh[t] += tmp;
        __syncthreads();
    }
    if (t < nblk) bbase[t] = sh[t] - v;       // exclusive base per block
    if (t == 255) offs[nNodes] = sh[255];     // grand total
}

__launch_bounds__(SCAN_B)
__global__ void scan_final_kernel(int* __restrict__ cnt, const int* __restrict__ bbase,
                                  int* __restrict__ offs, int n) {
    __shared__ int sh[SCAN_B];
    int id = (int)(blockIdx.x * SCAN_B + threadIdx.x);
    int v = (id < n) ? cnt[id] : 0;
    sh[threadIdx.x] = v;
    __syncthreads();
    for (int off = 1; off < SCAN_B; off <<= 1) {
        int tmp = ((int)threadIdx.x >= off) ? sh[threadIdx.x - off] : 0;
        __syncthreads();
        sh[threadIdx.x] += tmp;
        __syncthreads();
    }
    if (id < n) {
        int excl = sh[threadIdx.x] - v + bbase[blockIdx.x];
        offs[id] = excl;
        cnt[id]  = excl;   // becomes the scatter cursor
    }
}

__global__ void scatter_kernel(const int* __restrict__ src, const int* __restrict__ dst,
                               const int* __restrict__ et, const float* __restrict__ norm,
                               int* __restrict__ cursor, uint2* __restrict__ rec, int nE) {
    for (int e = (int)(blockIdx.x * blockDim.x + threadIdx.x); e < nE;
         e += (int)(gridDim.x * blockDim.x)) {
        int p = atomicAdd(&cursor[dst[e]], 1);
        rec[p] = make_uint2((uint32_t)src[e] | ((uint32_t)et[e] << 20), asu(norm[e]));
    }
}

// ---------------------------------------------------------------------------
// Input-space aggregation: G[d][i][b] = sum_{e in in(d)} norm_e*coeff[r_e,b]*x[src_e,i]
// One wave per dst node; lane = i. Unroll-4 (4 independent rec->x chains),
// cached (non-NT) loads: rec[j..j+3] share a cache line; coeff table is L1-hot.
// ---------------------------------------------------------------------------
__launch_bounds__(256)
__global__ void csr_agg_kernel(const uint16_t* __restrict__ x,
                               const float* __restrict__ coeff,
                               const int* __restrict__ offs,
                               const uint2* __restrict__ rec,
                               uint16_t* __restrict__ G, int nNodes) {
    const int lane = threadIdx.x & 63;
    const int wid  = (int)((blockIdx.x * blockDim.x + threadIdx.x) >> 6);
    const int nw   = (int)((gridDim.x * blockDim.x) >> 6);
    for (int d = wid; d < nNodes; d += nw) {
        const int j0 = offs[d], j1 = offs[d + 1];
        float acc[NB] = {0.f, 0.f, 0.f, 0.f, 0.f, 0.f, 0.f, 0.f};
        int j = j0;
        for (; j + 4 <= j1; j += 4) {
            const uint2 r0 = rec[j];
            const uint2 r1 = rec[j + 1];
            const uint2 r2 = rec[j + 2];
            const uint2 r3 = rec[j + 3];
            const float xv0 = asf((uint32_t)x[(size_t)(r0.x & 0xFFFFFu) * HDIM + lane] << 16);
            const float xv1 = asf((uint32_t)x[(size_t)(r1.x & 0xFFFFFu) * HDIM + lane] << 16);
            const float xv2 = asf((uint32_t)x[(size_t)(r2.x & 0xFFFFFu) * HDIM + lane] << 16);
            const float xv3 = asf((uint32_t)x[(size_t)(r3.x & 0xFFFFFu) * HDIM + lane] << 16);
            const float4 cA0 = *reinterpret_cast<const float4*>(coeff + (r0.x >> 20) * NB);
            const float4 cB0 = *reinterpret_cast<const float4*>(coeff + (r0.x >> 20) * NB + 4);
            const float4 cA1 = *reinterpret_cast<const float4*>(coeff + (r1.x >> 20) * NB);
            const float4 cB1 = *reinterpret_cast<const float4*>(coeff + (r1.x >> 20) * NB + 4);
            const float4 cA2 = *reinterpret_cast<const float4*>(coeff + (r2.x >> 20) * NB);
            const float4 cB2 = *reinterpret_cast<const float4*>(coeff + (r2.x >> 20) * NB + 4);
            const float4 cA3 = *reinterpret_cast<const float4*>(coeff + (r3.x >> 20) * NB);
            const float4 cB3 = *reinterpret_cast<const float4*>(coeff + (r3.x >> 20) * NB + 4);
            fmaC(cA0, cB0, asf(r0.y) * xv0, acc);
            fmaC(cA1, cB1, asf(r1.y) * xv1, acc);
            fmaC(cA2, cB2, asf(r2.y) * xv2, acc);
            fmaC(cA3, cB3, asf(r3.y) * xv3, acc);
        }
        for (; j < j1; j++) {
            const uint2 r0 = rec[j];
            const float xv0 = asf((uint32_t)x[(size_t)(r0.x & 0xFFFFFu) * HDIM + lane] << 16);
            const float4 cA0 = *reinterpret_cast<const float4*>(coeff + (r0.x >> 20) * NB);
            const float4 cB0 = *reinterpret_cast<const float4*>(coeff + (r0.x >> 20) * NB + 4);
            fmaC(cA0, cB0, asf(r0.y) * xv0, acc);
        }
        uint4 pv;
        pv.x = pack2(acc[0], acc[1]);
        pv.y = pack2(acc[2], acc[3]);
        pv.z = pack2(acc[4], acc[5]);
        pv.w = pack2(acc[6], acc[7]);
        *reinterpret_cast<uint4*>(G + (size_t)d * KDIM + lane * NB) = pv;
    }
}

// ---------------------------------------------------------------------------
// MFMA GEMM (round-4 known-good form): [N,512] bf16 (G) x [512,DOUT] bf16
// (bases swizzled to B-frag order in LDS). mfma_f32_16x16x32_bf16:
//   A[m=lane&15][k=(lane>>4)*8+j], B[k][n=lane&15], C col=lane&15,
//   row=(lane>>4)*4+reg. Block = 4 waves, 64-node tile.
// ---------------------------------------------------------------------------
__launch_bounds__(256)
__global__ void proj_hidden_kernel(const uint16_t* __restrict__ G,
                                   const float* __restrict__ bases,
                                   const float* __restrict__ bias,
                                   uint16_t* __restrict__ xout, int nNodes) {
    constexpr int OT = HDIM / 16;       // 4 o-tiles
    __shared__ __align__(16) uint16_t Wf[16 * OT * 64 * 8];   // 64 KB

    const int t    = (int)threadIdx.x;
    const int lane = t & 63;
    const int w    = t >> 6;
    const int q    = lane >> 4;
    const int c    = lane & 15;

    for (int idx = t; idx < 16 * OT * 64 * 8; idx += 256) {
        int j    = idx & 7;
        int ln   = (idx >> 3) & 63;
        int rest = idx >> 9;            // kb*OT + ot
        int ot   = rest & (OT - 1);
        int kb   = rest >> 2;
        int k    = kb * 32 + (ln >> 4) * 8 + j;
        int o    = ot * 16 + (ln & 15);
        int i    = k >> 3, b = k & 7;
        Wf[idx] = f2bf(bases[(size_t)(b * HDIM + i) * HDIM + o]);
    }
    __syncthreads();

    float bv[OT];
#pragma unroll
    for (int ot = 0; ot < OT; ot++) bv[ot] = bias[ot * 16 + c];

    const int nTiles = (nNodes + 63) / 64;
    for (int tile = blockIdx.x; tile < nTiles; tile += gridDim.x) {
        const int n0w = tile * 64 + w * 16;
        int arow = n0w + c;
        if (arow > nNodes - 1) arow = nNodes - 1;
        const uint16_t* gp = G + (size_t)arow * KDIM + q * 8;

        f32x4 acc[OT];
#pragma unroll
        for (int ot = 0; ot < OT; ot++) acc[ot] = {0.f, 0.f, 0.f, 0.f};

#pragma unroll
        for (int kb = 0; kb < 16; kb++) {
            FragU a;
            a.u = *reinterpret_cast<const uint4*>(gp + kb * 32);
#pragma unroll
            for (int ot = 0; ot < OT; ot++) {
                FragU b;
                b.u = *reinterpret_cast<const uint4*>(Wf + ((kb * OT + ot) * 64 + lane) * 8);
                acc[ot] = __builtin_amdgcn_mfma_f32_16x16x32_bf16(a.s, b.s, acc[ot], 0, 0, 0);
            }
        }

#pragma unroll
        for (int r = 0; r < 4; r++) {
            const int node = n0w + q * 4 + r;
            if (node < nNodes) {
#pragma unroll
                for (int ot = 0; ot < OT; ot++) {
                    float v = fmaxf(acc[ot][r] + bv[ot], 0.f);
                    xout[(size_t)node * HDIM + ot * 16 + c] = f2bf(v);
                }
            }
        }
    }
}

__launch_bounds__(256)
__global__ void proj_out_kernel(const uint16_t* __restrict__ G,
                                const float* __restrict__ bases,
                                const float* __restrict__ bias,
                                float* __restrict__ out, int nNodes) {
    __shared__ __align__(16) uint16_t Wf[16 * 64 * 8];   // 16 KB

    const int t    = (int)threadIdx.x;
    const int lane = t & 63;
    const int w    = t >> 6;
    const int q    = lane >> 4;
    const int c    = lane & 15;

    for (int idx = t; idx < 16 * 64 * 8; idx += 256) {
        int j  = idx & 7;
        int ln = (idx >> 3) & 63;
        int kb = idx >> 9;
        int k  = kb * 32 + (ln >> 4) * 8 + j;
        int o  = ln & 15;
        int i  = k >> 3, b = k & 7;
        Wf[idx] = f2bf(bases[(size_t)(b * HDIM + i) * ODIM + o]);
    }
    __syncthreads();

    const float bv = bias[c];

    const int nTiles = (nNodes + 63) / 64;
    for (int tile = blockIdx.x; tile < nTiles; tile += gridDim.x) {
        const int n0w = tile * 64 + w * 16;
        int arow = n0w + c;
        if (arow > nNodes - 1) arow = nNodes - 1;
        const uint16_t* gp = G + (size_t)arow * KDIM + q * 8;

        f32x4 acc = {0.f, 0.f, 0.f, 0.f};
#pragma unroll
        for (int kb = 0; kb < 16; kb++) {
            FragU a, b;
            a.u = *reinterpret_cast<const uint4*>(gp + kb * 32);
            b.u = *reinterpret_cast<const uint4*>(Wf + (kb * 64 + lane) * 8);
            acc = __builtin_amdgcn_mfma_f32_16x16x32_bf16(a.s, b.s, acc, 0, 0, 0);
        }

#pragma unroll
        for (int r = 0; r < 4; r++) {
            const int node = n0w + q * 4 + r;
            if (node < nNodes) out[(size_t)node * ODIM + c] = acc[r] + bv;
        }
    }
}

extern "C" void kernel_launch(void* const* d_in, const int* in_sizes, int n_in,
                              void* d_out, int out_size, void* d_ws, size_t ws_size,
                              hipStream_t stream) {
    const float* feats  = (const float*)d_in[0];
    const float* coeff0 = (const float*)d_in[1];
    const float* bases0 = (const float*)d_in[2];
    const float* bias0  = (const float*)d_in[3];
    const float* coeff1 = (const float*)d_in[4];
    const float* bases1 = (const float*)d_in[5];
    const float* bias1  = (const float*)d_in[6];
    const float* coeff2 = (const float*)d_in[7];
    const float* bases2 = (const float*)d_in[8];
    const float* bias2  = (const float*)d_in[9];
    const int*   src    = (const int*)d_in[10];
    const int*   dst    = (const int*)d_in[11];
    const int*   etype  = (const int*)d_in[12];
    const float* norm   = (const float*)d_in[13];
    float* out = (float*)d_out;

    char* base = (char*)d_ws;
    // layout: G 102.4MB | x 12.8MB | offs | cursor | bsum | bbase | rec 8MB
    uint16_t* G = (uint16_t*)base;
    uint16_t* x = (uint16_t*)(base + (size_t)NNODES * KDIM * 2);       // +102,400,000
    const size_t OFF_OFFS  = 115200000;
    const size_t OFF_CURS  = OFF_OFFS + 400016;
    const size_t OFF_BSUM  = OFF_CURS + 400016;
    const size_t OFF_BBASE = OFF_BSUM + 1024;
    const size_t OFF_REC   = OFF_BBASE + 1024;                         // 116,002,080
    int*   offs  = (int*)(base + OFF_OFFS);
    int*   curs  = (int*)(base + OFF_CURS);
    int*   bsum  = (int*)(base + OFF_BSUM);
    int*   bbase = (int*)(base + OFF_BBASE);
    uint2* rec   = (uint2*)(base + OFF_REC);

    const int nblk = (NNODES + SCAN_B - 1) / SCAN_B;   // 196 <= 256

    // ---- CSR build (graph identical across layers; built once per call)
    hipLaunchKernelGGL(zero_kernel, dim3(256), dim3(256), 0, stream, curs, NNODES);
    hipLaunchKernelGGL(hist_kernel, dim3(2048), dim3(256), 0, stream, dst, curs, NEDGES);
    hipLaunchKernelGGL(scan_partial_kernel, dim3(nblk), dim3(SCAN_B), 0, stream, curs, bsum, NNODES);
    hipLaunchKernelGGL(scan_base_kernel, dim3(1), dim3(256), 0, stream, bsum, bbase, offs, nblk, NNODES);
    hipLaunchKernelGGL(scan_final_kernel, dim3(nblk), dim3(SCAN_B), 0, stream, curs, bbase, offs, NNODES);
    hipLaunchKernelGGL(scatter_kernel, dim3(2048), dim3(256), 0, stream,
                       src, dst, etype, norm, curs, rec, NEDGES);

    // ---- x0 = bf16(feats)
    hipLaunchKernelGGL(cast_kernel, dim3(2048), dim3(256), 0, stream,
                       feats, x, NNODES * HDIM / 4);

    // ---- Layer 0
    hipLaunchKernelGGL(csr_agg_kernel, dim3(2048), dim3(256), 0, stream,
                       x, coeff0, offs, rec, G, NNODES);
    hipLaunchKernelGGL(proj_hidden_kernel, dim3(512), dim3(256), 0, stream,
                       G, bases0, bias0, x, NNODES);
    // ---- Layer 1
    hipLaunchKernelGGL(csr_agg_kernel, dim3(2048), dim3(256), 0, stream,
                       x, coeff1, offs, rec, G, NNODES);
    hipLaunchKernelGGL(proj_hidden_kernel, dim3(512), dim3(256), 0, stream,
                       G, bases1, bias1, x, NNODES);
    // ---- Layer 2
    hipLaunchKernelGGL(csr_agg_kernel, dim3(2048), dim3(256), 0, stream,
                       x, coeff2, offs, rec, G, NNODES);
    hipLaunchKernelGGL(proj_out_kernel, dim3(512), dim3(256), 0, stream,
                       G, bases2, bias2, out, NNODES);
}

// Round 7
// 550.106 us; speedup vs baseline: 1.5152x; 1.2589x over previous
//
#include <hip/hip_runtime.h>
#include <hip/hip_bf16.h>
#include <cstdint>

#define NNODES 100000
#define NEDGES 1000000
#define HDIM 64
#define ODIM 16
#define NB 8
#define KDIM (HDIM * NB)   // 512 = GEMM inner dim, k = i*8 + b

typedef short short8 __attribute__((ext_vector_type(8)));
typedef float f32x4  __attribute__((ext_vector_type(4)));
union FragU { uint4 u; short8 s; };

__device__ __forceinline__ float asf(uint32_t u) { float f; __builtin_memcpy(&f, &u, 4); return f; }
__device__ __forceinline__ uint32_t asu(float f) { uint32_t u; __builtin_memcpy(&u, &f, 4); return u; }
__device__ __forceinline__ uint16_t f2bf(float f) {
    uint32_t x = asu(f);
    return (uint16_t)((x + 0x7FFFu + ((x >> 16) & 1u)) >> 16);
}
__device__ __forceinline__ uint32_t pack2(float lo, float hi) {
    return (uint32_t)f2bf(lo) | ((uint32_t)f2bf(hi) << 16);
}
__device__ __forceinline__ void fmaC(const float4& cA, const float4& cB, float xs,
                                     float* __restrict__ acc) {
    acc[0] = fmaf(cA.x, xs, acc[0]); acc[1] = fmaf(cA.y, xs, acc[1]);
    acc[2] = fmaf(cA.z, xs, acc[2]); acc[3] = fmaf(cA.w, xs, acc[3]);
    acc[4] = fmaf(cB.x, xs, acc[4]); acc[5] = fmaf(cB.y, xs, acc[5]);
    acc[6] = fmaf(cB.z, xs, acc[6]); acc[7] = fmaf(cB.w, xs, acc[7]);
}

// ---------------------------------------------------------------------------
// cast: f32 feats -> bf16 x  (4 elems/thread)
// ---------------------------------------------------------------------------
__global__ void cast_kernel(const float* __restrict__ in, uint16_t* __restrict__ out, int n4) {
    const int stride = (int)(gridDim.x * blockDim.x);
    for (int idx = (int)(blockIdx.x * blockDim.x + threadIdx.x); idx < n4; idx += stride) {
        float4 v = reinterpret_cast<const float4*>(in)[idx];
        uint2 p;
        p.x = pack2(v.x, v.y);
        p.y = pack2(v.z, v.w);
        reinterpret_cast<uint2*>(out)[idx] = p;
    }
}

// ---------------------------------------------------------------------------
// CSR build: histogram by dst -> exclusive scan -> scatter packed edge recs
// rec[e] = { src | (etype<<20), norm }  (8 B)
// ---------------------------------------------------------------------------
__global__ void zero_kernel(int* __restrict__ p, int n) {
    for (int i = (int)(blockIdx.x * blockDim.x + threadIdx.x); i < n;
         i += (int)(gridDim.x * blockDim.x)) p[i] = 0;
}

__global__ void hist_kernel(const int* __restrict__ dst, int* __restrict__ cnt, int nE) {
    for (int e = (int)(blockIdx.x * blockDim.x + threadIdx.x); e < nE;
         e += (int)(gridDim.x * blockDim.x)) atomicAdd(&cnt[dst[e]], 1);
}

#define SCAN_B 512
__launch_bounds__(SCAN_B)
__global__ void scan_partial_kernel(const int* __restrict__ cnt, int* __restrict__ bsum, int n) {
    __shared__ int sh[SCAN_B];
    int id = (int)(blockIdx.x * SCAN_B + threadIdx.x);
    sh[threadIdx.x] = (id < n) ? cnt[id] : 0;
    __syncthreads();
    for (int off = SCAN_B / 2; off > 0; off >>= 1) {
        if ((int)threadIdx.x < off) sh[threadIdx.x] += sh[threadIdx.x + off];
        __syncthreads();
    }
    if (threadIdx.x == 0) bsum[blockIdx.x] = sh[0];
}

// parallel scan over block sums (nblk <= 256), one block of 256 threads
__launch_bounds__(256)
__global__ void scan_base_kernel(const int* __restrict__ bsum, int* __restrict__ bbase,
                                 int* __restrict__ offs, int nblk, int nNodes) {
    __shared__ int sh[256];
    const int t = (int)threadIdx.x;
    int v = (t < nblk) ? bsum[t] : 0;
    sh[t] = v;
    __syncthreads();
    for (int off = 1; off < 256; off <<= 1) {
        int tmp = (t >= off) ? sh[t - off] : 0;
        __syncthreads();
        sh[t] += tmp;
        __syncthreads();
    }
    if (t < nblk) bbase[t] = sh[t] - v;       // exclusive base per block
    if (t == 255) offs[nNodes] = sh[255];     // grand total
}

__launch_bounds__(SCAN_B)
__global__ void scan_final_kernel(int* __restrict__ cnt, const int* __restrict__ bbase,
                                  int* __restrict__ offs, int n) {
    __shared__ int sh[SCAN_B];
    int id = (int)(blockIdx.x * SCAN_B + threadIdx.x);
    int v = (id < n) ? cnt[id] : 0;
    sh[threadIdx.x] = v;
    __syncthreads();
    for (int off = 1; off < SCAN_B; off <<= 1) {
        int tmp = ((int)threadIdx.x >= off) ? sh[threadIdx.x - off] : 0;
        __syncthreads();
        sh[threadIdx.x] += tmp;
        __syncthreads();
    }
    if (id < n) {
        int excl = sh[threadIdx.x] - v + bbase[blockIdx.x];
        offs[id] = excl;
        cnt[id]  = excl;   // becomes the scatter cursor
    }
}

__global__ void scatter_kernel(const int* __restrict__ src, const int* __restrict__ dst,
                               const int* __restrict__ et, const float* __restrict__ norm,
                               int* __restrict__ cursor, uint2* __restrict__ rec, int nE) {
    for (int e = (int)(blockIdx.x * blockDim.x + threadIdx.x); e < nE;
         e += (int)(gridDim.x * blockDim.x)) {
        int p = atomicAdd(&cursor[dst[e]], 1);
        rec[p] = make_uint2((uint32_t)src[e] | ((uint32_t)et[e] << 20), asu(norm[e]));
    }
}

// ---------------------------------------------------------------------------
// Input-space aggregation: G[d][i][b] = sum_{e in in(d)} norm_e*coeff[r_e,b]*x[src_e,i]
// HALF-WAVE per dst node: lane hl in [0,32) covers i = 2*hl, 2*hl+1 via one
// dword x-load. Two nodes per wave + unroll-4 each = 8 independent gather
// chains in flight; VMEM instructions per edge halved vs wave-per-node.
// FMA order per (i,b) identical to previous rounds -> bit-identical output.
// ---------------------------------------------------------------------------
__launch_bounds__(256)
__global__ void csr_agg_kernel(const uint16_t* __restrict__ x,
                               const float* __restrict__ coeff,
                               const int* __restrict__ offs,
                               const uint2* __restrict__ rec,
                               uint16_t* __restrict__ G, int nNodes) {
    const int hl   = (int)threadIdx.x & 31;   // lane within half-wave
    const int hwid = (int)((blockIdx.x * blockDim.x + threadIdx.x) >> 5);
    const int nhw  = (int)((gridDim.x * blockDim.x) >> 5);
    for (int d = hwid; d < nNodes; d += nhw) {
        const int j0 = offs[d], j1 = offs[d + 1];
        float accL[NB] = {0.f, 0.f, 0.f, 0.f, 0.f, 0.f, 0.f, 0.f};  // i = 2*hl
        float accH[NB] = {0.f, 0.f, 0.f, 0.f, 0.f, 0.f, 0.f, 0.f};  // i = 2*hl+1
        int j = j0;
        for (; j + 4 <= j1; j += 4) {
            const uint2 r0 = rec[j];
            const uint2 r1 = rec[j + 1];
            const uint2 r2 = rec[j + 2];
            const uint2 r3 = rec[j + 3];
            const uint32_t w0 = *reinterpret_cast<const uint32_t*>(
                x + (size_t)(r0.x & 0xFFFFFu) * HDIM + 2 * hl);
            const uint32_t w1 = *reinterpret_cast<const uint32_t*>(
                x + (size_t)(r1.x & 0xFFFFFu) * HDIM + 2 * hl);
            const uint32_t w2 = *reinterpret_cast<const uint32_t*>(
                x + (size_t)(r2.x & 0xFFFFFu) * HDIM + 2 * hl);
            const uint32_t w3 = *reinterpret_cast<const uint32_t*>(
                x + (size_t)(r3.x & 0xFFFFFu) * HDIM + 2 * hl);

            {
                const float4 cA = *reinterpret_cast<const float4*>(coeff + (r0.x >> 20) * NB);
                const float4 cB = *reinterpret_cast<const float4*>(coeff + (r0.x >> 20) * NB + 4);
                const float nm = asf(r0.y);
                fmaC(cA, cB, asf(w0 << 16) * nm, accL);
                fmaC(cA, cB, asf(w0 & 0xFFFF0000u) * nm, accH);
            }
            {
                const float4 cA = *reinterpret_cast<const float4*>(coeff + (r1.x >> 20) * NB);
                const float4 cB = *reinterpret_cast<const float4*>(coeff + (r1.x >> 20) * NB + 4);
                const float nm = asf(r1.y);
                fmaC(cA, cB, asf(w1 << 16) * nm, accL);
                fmaC(cA, cB, asf(w1 & 0xFFFF0000u) * nm, accH);
            }
            {
                const float4 cA = *reinterpret_cast<const float4*>(coeff + (r2.x >> 20) * NB);
                const float4 cB = *reinterpret_cast<const float4*>(coeff + (r2.x >> 20) * NB + 4);
                const float nm = asf(r2.y);
                fmaC(cA, cB, asf(w2 << 16) * nm, accL);
                fmaC(cA, cB, asf(w2 & 0xFFFF0000u) * nm, accH);
            }
            {
                const float4 cA = *reinterpret_cast<const float4*>(coeff + (r3.x >> 20) * NB);
                const float4 cB = *reinterpret_cast<const float4*>(coeff + (r3.x >> 20) * NB + 4);
                const float nm = asf(r3.y);
                fmaC(cA, cB, asf(w3 << 16) * nm, accL);
                fmaC(cA, cB, asf(w3 & 0xFFFF0000u) * nm, accH);
            }
        }
        for (; j < j1; j++) {
            const uint2 r0 = rec[j];
            const uint32_t w0 = *reinterpret_cast<const uint32_t*>(
                x + (size_t)(r0.x & 0xFFFFFu) * HDIM + 2 * hl);
            const float4 cA = *reinterpret_cast<const float4*>(coeff + (r0.x >> 20) * NB);
            const float4 cB = *reinterpret_cast<const float4*>(coeff + (r0.x >> 20) * NB + 4);
            const float nm = asf(r0.y);
            fmaC(cA, cB, asf(w0 << 16) * nm, accL);
            fmaC(cA, cB, asf(w0 & 0xFFFF0000u) * nm, accH);
        }
        // lane hl owns k = 16*hl .. 16*hl+15 (i=2hl -> b0..7, i=2hl+1 -> b0..7)
        uint4 lo, hi;
        lo.x = pack2(accL[0], accL[1]); lo.y = pack2(accL[2], accL[3]);
        lo.z = pack2(accL[4], accL[5]); lo.w = pack2(accL[6], accL[7]);
        hi.x = pack2(accH[0], accH[1]); hi.y = pack2(accH[2], accH[3]);
        hi.z = pack2(accH[4], accH[5]); hi.w = pack2(accH[6], accH[7]);
        uint16_t* gp = G + (size_t)d * KDIM + hl * 16;
        *reinterpret_cast<uint4*>(gp)     = lo;
        *reinterpret_cast<uint4*>(gp + 8) = hi;
    }
}

// ---------------------------------------------------------------------------
// MFMA GEMM (round-4 known-good form): [N,512] bf16 (G) x [512,DOUT] bf16
// (bases swizzled to B-frag order in LDS). mfma_f32_16x16x32_bf16:
//   A[m=lane&15][k=(lane>>4)*8+j], B[k][n=lane&15], C col=lane&15,
//   row=(lane>>4)*4+reg. Block = 4 waves, 64-node tile.
// ---------------------------------------------------------------------------
__launch_bounds__(256)
__global__ void proj_hidden_kernel(const uint16_t* __restrict__ G,
                                   const float* __restrict__ bases,
                                   const float* __restrict__ bias,
                                   uint16_t* __restrict__ xout, int nNodes) {
    constexpr int OT = HDIM / 16;       // 4 o-tiles
    __shared__ __align__(16) uint16_t Wf[16 * OT * 64 * 8];   // 64 KB

    const int t    = (int)threadIdx.x;
    const int lane = t & 63;
    const int w    = t >> 6;
    const int q    = lane >> 4;
    const int c    = lane & 15;

    for (int idx = t; idx < 16 * OT * 64 * 8; idx += 256) {
        int j    = idx & 7;
        int ln   = (idx >> 3) & 63;
        int rest = idx >> 9;            // kb*OT + ot
        int ot   = rest & (OT - 1);
        int kb   = rest >> 2;
        int k    = kb * 32 + (ln >> 4) * 8 + j;
        int o    = ot * 16 + (ln & 15);
        int i    = k >> 3, b = k & 7;
        Wf[idx] = f2bf(bases[(size_t)(b * HDIM + i) * HDIM + o]);
    }
    __syncthreads();

    float bv[OT];
#pragma unroll
    for (int ot = 0; ot < OT; ot++) bv[ot] = bias[ot * 16 + c];

    const int nTiles = (nNodes + 63) / 64;
    for (int tile = blockIdx.x; tile < nTiles; tile += gridDim.x) {
        const int n0w = tile * 64 + w * 16;
        int arow = n0w + c;
        if (arow > nNodes - 1) arow = nNodes - 1;
        const uint16_t* gp = G + (size_t)arow * KDIM + q * 8;

        f32x4 acc[OT];
#pragma unroll
        for (int ot = 0; ot < OT; ot++) acc[ot] = {0.f, 0.f, 0.f, 0.f};

#pragma unroll
        for (int kb = 0; kb < 16; kb++) {
            FragU a;
            a.u = *reinterpret_cast<const uint4*>(gp + kb * 32);
#pragma unroll
            for (int ot = 0; ot < OT; ot++) {
                FragU b;
                b.u = *reinterpret_cast<const uint4*>(Wf + ((kb * OT + ot) * 64 + lane) * 8);
                acc[ot] = __builtin_amdgcn_mfma_f32_16x16x32_bf16(a.s, b.s, acc[ot], 0, 0, 0);
            }
        }

#pragma unroll
        for (int r = 0; r < 4; r++) {
            const int node = n0w + q * 4 + r;
            if (node < nNodes) {
#pragma unroll
                for (int ot = 0; ot < OT; ot++) {
                    float v = fmaxf(acc[ot][r] + bv[ot], 0.f);
                    xout[(size_t)node * HDIM + ot * 16 + c] = f2bf(v);
                }
            }
        }
    }
}

__launch_bounds__(256)
__global__ void proj_out_kernel(const uint16_t* __restrict__ G,
                                const float* __restrict__ bases,
                                const float* __restrict__ bias,
                                float* __restrict__ out, int nNodes) {
    __shared__ __align__(16) uint16_t Wf[16 * 64 * 8];   // 16 KB

    const int t    = (int)threadIdx.x;
    const int lane = t & 63;
    const int w    = t >> 6;
    const int q    = lane >> 4;
    const int c    = lane & 15;

    for (int idx = t; idx < 16 * 64 * 8; idx += 256) {
        int j  = idx & 7;
        int ln = (idx >> 3) & 63;
        int kb = idx >> 9;
        int k  = kb * 32 + (ln >> 4) * 8 + j;
        int o  = ln & 15;
        int i  = k >> 3, b = k & 7;
        Wf[idx] = f2bf(bases[(size_t)(b * HDIM + i) * ODIM + o]);
    }
    __syncthreads();

    const float bv = bias[c];

    const int nTiles = (nNodes + 63) / 64;
    for (int tile = blockIdx.x; tile < nTiles; tile += gridDim.x) {
        const int n0w = tile * 64 + w * 16;
        int arow = n0w + c;
        if (arow > nNodes - 1) arow = nNodes - 1;
        const uint16_t* gp = G + (size_t)arow * KDIM + q * 8;

        f32x4 acc = {0.f, 0.f, 0.f, 0.f};
#pragma unroll
        for (int kb = 0; kb < 16; kb++) {
            FragU a, b;
            a.u = *reinterpret_cast<const uint4*>(gp + kb * 32);
            b.u = *reinterpret_cast<const uint4*>(Wf + (kb * 64 + lane) * 8);
            acc = __builtin_amdgcn_mfma_f32_16x16x32_bf16(a.s, b.s, acc, 0, 0, 0);
        }

#pragma unroll
        for (int r = 0; r < 4; r++) {
            const int node = n0w + q * 4 + r;
            if (node < nNodes) out[(size_t)node * ODIM + c] = acc[r] + bv;
        }
    }
}

extern "C" void kernel_launch(void* const* d_in, const int* in_sizes, int n_in,
                              void* d_out, int out_size, void* d_ws, size_t ws_size,
                              hipStream_t stream) {
    const float* feats  = (const float*)d_in[0];
    const float* coeff0 = (const float*)d_in[1];
    const float* bases0 = (const float*)d_in[2];
    const float* bias0  = (const float*)d_in[3];
    const float* coeff1 = (const float*)d_in[4];
    const float* bases1 = (const float*)d_in[5];
    const float* bias1  = (const float*)d_in[6];
    const float* coeff2 = (const float*)d_in[7];
    const float* bases2 = (const float*)d_in[8];
    const float* bias2  = (const float*)d_in[9];
    const int*   src    = (const int*)d_in[10];
    const int*   dst    = (const int*)d_in[11];
    const int*   etype  = (const int*)d_in[12];
    const float* norm   = (const float*)d_in[13];
    float* out = (float*)d_out;

    char* base = (char*)d_ws;
    // layout: G 102.4MB | x 12.8MB | offs | cursor | bsum | bbase | rec 8MB
    uint16_t* G = (uint16_t*)base;
    uint16_t* x = (uint16_t*)(base + (size_t)NNODES * KDIM * 2);       // +102,400,000
    const size_t OFF_OFFS  = 115200000;
    const size_t OFF_CURS  = OFF_OFFS + 400016;
    const size_t OFF_BSUM  = OFF_CURS + 400016;
    const size_t OFF_BBASE = OFF_BSUM + 1024;
    const size_t OFF_REC   = OFF_BBASE + 1024;                         // 116,002,080
    int*   offs  = (int*)(base + OFF_OFFS);
    int*   curs  = (int*)(base + OFF_CURS);
    int*   bsum  = (int*)(base + OFF_BSUM);
    int*   bbase = (int*)(base + OFF_BBASE);
    uint2* rec   = (uint2*)(base + OFF_REC);

    const int nblk = (NNODES + SCAN_B - 1) / SCAN_B;   // 196 <= 256

    // ---- CSR build (graph identical across layers; built once per call)
    hipLaunchKernelGGL(zero_kernel, dim3(256), dim3(256), 0, stream, curs, NNODES);
    hipLaunchKernelGGL(hist_kernel, dim3(2048), dim3(256), 0, stream, dst, curs, NEDGES);
    hipLaunchKernelGGL(scan_partial_kernel, dim3(nblk), dim3(SCAN_B), 0, stream, curs, bsum, NNODES);
    hipLaunchKernelGGL(scan_base_kernel, dim3(1), dim3(256), 0, stream, bsum, bbase, offs, nblk, NNODES);
    hipLaunchKernelGGL(scan_final_kernel, dim3(nblk), dim3(SCAN_B), 0, stream, curs, bbase, offs, NNODES);
    hipLaunchKernelGGL(scatter_kernel, dim3(2048), dim3(256), 0, stream,
                       src, dst, etype, norm, curs, rec, NEDGES);

    // ---- x0 = bf16(feats)
    hipLaunchKernelGGL(cast_kernel, dim3(2048), dim3(256), 0, stream,
                       feats, x, NNODES * HDIM / 4);

    // ---- Layer 0
    hipLaunchKernelGGL(csr_agg_kernel, dim3(2048), dim3(256), 0, stream,
                       x, coeff0, offs, rec, G, NNODES);
    hipLaunchKernelGGL(proj_hidden_kernel, dim3(512), dim3(256), 0, stream,
                       G, bases0, bias0, x, NNODES);
    // ---- Layer 1
    hipLaunchKernelGGL(csr_agg_kernel, dim3(2048), dim3(256), 0, stream,
                       x, coeff1, offs, rec, G, NNODES);
    hipLaunchKernelGGL(proj_hidden_kernel, dim3(512), dim3(256), 0, stream,
                       G, bases1, bias1, x, NNODES);
    // ---- Layer 2
    hipLaunchKernelGGL(csr_agg_kernel, dim3(2048), dim3(256), 0, stream,
                       x, coeff2, offs, rec, G, NNODES);
    hipLaunchKernelGGL(proj_out_kernel, dim3(512), dim3(256), 0, stream,
                       G, bases2, bias2, out, NNODES);
}